// Round 6
// baseline (4476.365 us; speedup 1.0000x reference)
//
#include <hip/hip_runtime.h>

#define NTHR 1024
#define NB   16
#define NOSC 50
#define NPER 40
#define KTOT 2000
#define KPAD 2048
#define NSTEP 700
#define BATCH 4096
#define HALF_PI 1.57079632679489662f
#define ACT_OFF ((size_t)NSTEP * BATCH * 4)

typedef _Float16 v8h __attribute__((ext_vector_type(8)));
typedef _Float16 h2_t __attribute__((ext_vector_type(2)));
typedef float v4f __attribute__((ext_vector_type(4)));

__device__ _Float16 g_w4[32 * KPAD];    // fc4_w in f16, zero-padded K 2000->2048

__device__ __forceinline__ float fdot2f(float a_bits, float b_bits, float acc) {
    h2_t a = __builtin_bit_cast(h2_t, a_bits);
    h2_t b = __builtin_bit_cast(h2_t, b_bits);
#if __has_builtin(__builtin_amdgcn_fdot2)
    return __builtin_amdgcn_fdot2(a, b, acc, false);
#else
    return fmaf((float)a[0], (float)b[0], fmaf((float)a[1], (float)b[1], acc));
#endif
}

__device__ __forceinline__ float dot4(float4 a, float4 b, float acc) {
    acc = fmaf(a.x, b.x, acc);
    acc = fmaf(a.y, b.y, acc);
    acc = fmaf(a.z, b.z, acc);
    acc = fmaf(a.w, b.w, acc);
    return acc;
}

__device__ __forceinline__ float pkrtz(float a, float b) {
    auto q = __builtin_amdgcn_cvt_pkrtz(a, b);
    return __builtin_bit_cast(float, q);
}

__global__ void prep_f16(const float* __restrict__ fc4_w) {
    int tid = blockIdx.x * blockDim.x + threadIdx.x;   // 65536 total
    int j = tid >> 11, k = tid & 2047;
    g_w4[j * KPAD + k] = (k < KTOT) ? (_Float16)fc4_w[j * KTOT + k] : (_Float16)0.f;
}

// act layout (A-fragment-major, per k-step block of 32 k):
//   element (b, k): oct = k>>3, j = k&7, slot = b ^ (oct & 15)
//   f16 idx = (oct>>2)*512 + (oct&3)*128 + slot*8 + j
__global__ __launch_bounds__(NTHR)
void net_main(const float* __restrict__ x,
              const float* __restrict__ fc1_w, const float* __restrict__ fc1_b,
              const float* __restrict__ fc2_w, const float* __restrict__ fc2_b,
              const float* __restrict__ fc3_w, const float* __restrict__ fc3_b,
              const float* __restrict__ fcd_w, const float* __restrict__ fcd_b,
              const float* __restrict__ enc,   const float* __restrict__ osc_bias,
              const float* __restrict__ dec,
              const float* __restrict__ fc4_b,
              const float* __restrict__ fc5_w, const float* __restrict__ fc5_b,
              float* __restrict__ out)
{
    __shared__ __align__(16) _Float16 act_sh[64 * 512];   // 64 KB, frag-major
    __shared__ __align__(16) float part[16 * 2 * 256];    // 32 KB, MFMA partials
    __shared__ __align__(16) float os_sh[NOSC * NB * 2];  // 6.4 KB [o][b*2+d]
    __shared__ __align__(16) float enc_sh[4096];          // 16 KB
    __shared__ __align__(16) float bias_sh[2048];         // 8 KB
    __shared__ __align__(16) _Float16 dec_sh[4096];       // 8 KB
    __shared__ __align__(16) float dir[NB * 2];

    const int t    = threadIdx.x;
    const int lane = t & 63;
    const int wv   = t >> 6;            // 0..15 == batch owned in phase C
    const int b0   = blockIdx.x * NB;

    float* h  = (float*)act_sh;         // [NB][128] f32 temp (pre-loop only)
    float* h2 = (float*)act_sh + NB * 128;

    // ---------- stage constants to LDS ----------
    for (int i = t; i < 4000; i += NTHR) enc_sh[i]  = enc[i];
    for (int i = t; i < 2000; i += NTHR) bias_sh[i] = osc_bias[i];
    for (int i = t; i < 4000; i += NTHR) dec_sh[i]  = (_Float16)dec[i];

    // ---------- precompute: fc1 ----------
    #pragma unroll
    for (int ii = 0; ii < 2; ++ii) {
        int task = t + ii * NTHR;       // 2048 tasks
        int b = task >> 7, i = task & 127;
        float x0 = x[(b0 + b) * 2 + 0];
        float x1 = x[(b0 + b) * 2 + 1];
        float v = fmaf(x0, fc1_w[2 * i], fmaf(x1, fc1_w[2 * i + 1], fc1_b[i]));
        h[b * 128 + i] = fmaxf(v, 0.f);
    }
    __syncthreads();
    // ---------- precompute: fc2 -> h2, fcd -> dir ----------
    #pragma unroll
    for (int ii = 0; ii < 2; ++ii) {
        int task = t + ii * NTHR;
        int b = task >> 7, i = task & 127;
        float acc = fc2_b[i];
        #pragma unroll 4
        for (int k = 0; k < 128; k += 4)
            acc = dot4(*(const float4*)&fc2_w[i * 128 + k],
                       *(const float4*)&h[b * 128 + k], acc);
        h2[b * 128 + i] = fmaxf(acc, 0.f);
    }
    if (t < NB * 2) {
        int b = t >> 1, j = t & 1;
        float acc = fcd_b[j];
        #pragma unroll 4
        for (int k = 0; k < 128; k += 4)
            acc = dot4(*(const float4*)&fcd_w[j * 128 + k],
                       *(const float4*)&h[b * 128 + k], acc);
        dir[b * 2 + j] = acc;
    }
    __syncthreads();
    // per-wave limb constants (all lanes)
    float bs0 = dir[wv * 2 + 0] + fc5_b[0];
    float bs1 = dir[wv * 2 + 1] + fc5_b[1];
    // ---------- precompute: fc3 -> os_sh ----------
    #pragma unroll
    for (int ii = 0; ii < 2; ++ii) {
        int task = t + ii * NTHR;
        if (task < NOSC * NB * 2) {     // 1600 tasks
            int o = task >> 5, r = task & 31, b = r >> 1;
            int row = o * 2 + (r & 1);
            float acc = fc3_b[row];
            #pragma unroll 4
            for (int k = 0; k < 128; k += 4)
                acc = dot4(*(const float4*)&fc3_w[row * 128 + k],
                           *(const float4*)&h2[b * 128 + k], acc);
            os_sh[o * 32 + r] = acc;
        }
    }
    // ---------- limb init (per-wave, all lanes redundant) ----------
    float theta = x[(b0 + wv) * 2 + 0];
    float omega = 0.f;
    float l1 = fmaf(-0.02f, theta, 0.1f);
    float l2 = fmaf( 0.02f, theta, 0.1f);
    // zero act padding (octets 250..255 -> f16 idx [32000, 32768))
    if (t < 768) act_sh[32000 + t] = (_Float16)0.f;

    // ---------- loop-invariant indices / registers ----------
    const int n_col = lane & 15, quad = lane >> 4;
    const _Float16* wp = &g_w4[n_col * KPAD + wv * 128 + quad * 8];
    int a_off[4];
    #pragma unroll
    for (int ks4 = 0; ks4 < 4; ++ks4) {
        int oct15 = ((wv * 4 + ks4) * 4 + quad) & 15;
        a_off[ks4] = (wv * 4 + ks4) * 512 + quad * 128 + ((n_col ^ oct15) * 8);
    }
    const int jC      = lane & 31;
    const int halfC   = lane >> 5;
    const int baseC   = (jC >> 4) * 256 + (wv >> 2) * 64 + (jC & 15) * 4 + (wv & 3);
    const float fc4bC = fc4_b[jC];
    const float fw0   = fc5_w[jC];
    const float fw1   = fc5_w[32 + jC];
    __syncthreads();

    // per-wave phase C for step sc (all 64 lanes participate; lane0 stores)
    auto do_C = [&](int sc) {
        float v = 0.f;
        #pragma unroll
        for (int w = 0; w < 8; ++w)
            v += part[(halfC * 8 + w) * 512 + baseC];
        v += __shfl_xor(v, 32, 64);
        float b1 = fmaxf(v + fc4bC, 0.f);
        float p0 = b1 * fw0, p1 = b1 * fw1;
        #pragma unroll
        for (int m = 16; m >= 1; m >>= 1) {
            p0 += __shfl_xor(p0, m, 64);
            p1 += __shfl_xor(p1, m, 64);
        }
        float a0 = bs0 + p0, a1 = bs1 + p1;
        float f1v = fmaxf(a0, 0.f) * 50.f * fmaxf(l1 - 0.05f, 0.f);
        float f2v = fmaxf(a1, 0.f) * 50.f * fmaxf(l2 - 0.05f, 0.f);
        float domega = (0.02f * (f2v - f1v) - 0.01f * omega) / 0.001f;
        float dl1 = ((0.1f - 0.02f * theta) - l1) / 0.05f;
        float dl2 = ((0.1f + 0.02f * theta) - l2) / 0.05f;
        float pos = fmaf(0.001f, omega,  theta);
        float vel = fmaf(0.001f, domega, omega);
        l1 = fmaf(0.001f, dl1, l1);
        l2 = fmaf(0.001f, dl2, l2);
        bool inb = (pos > -HALF_PI) && (pos < HALF_PI);
        float posc = fminf(fmaxf(pos, -HALF_PI), HALF_PI);
        vel = inb ? vel : 0.f;
        theta = posc;
        omega = vel;
        if (lane == 0) {
            float4 lo; lo.x = posc; lo.y = vel; lo.z = l1; lo.w = l2;
            *(float4*)&out[((size_t)sc * BATCH + (b0 + wv)) * 4] = lo;
            float2 ao; ao.x = a0; ao.y = a1;
            *(float2*)&out[ACT_OFF + ((size_t)sc * BATCH + (b0 + wv)) * 2] = ao;
        }
    };

    for (int s = 0; s < NSTEP; ++s) {
        // ---- segment 1: C(s-1) (per-wave) overlapped with phase A(s) ----
        if (s > 0) do_C(s - 1);

        #pragma unroll
        for (int ii = 0; ii < 4; ++ii) {
            int task = t + ii * NTHR;
            int oct = task >> 4;            // 0..255
            int b   = task & 15;
            if (oct < 250) {
                int o = oct / 5;
                float2 osv = *(const float2*)&os_sh[o * 32 + b * 2];
                const float* ep = &enc_sh[oct * 16];
                const float* bp = &bias_sh[oct * 8];
                float4 e0 = *(const float4*)&ep[0];
                float4 e1 = *(const float4*)&ep[4];
                float4 e2 = *(const float4*)&ep[8];
                float4 e3 = *(const float4*)&ep[12];
                float4 bi0 = *(const float4*)&bp[0];
                float4 bi1 = *(const float4*)&bp[4];
                float r0 = fmaxf(fmaf(e0.x, osv.x, fmaf(e0.y, osv.y, bi0.x)), 0.f);
                float r1 = fmaxf(fmaf(e0.z, osv.x, fmaf(e0.w, osv.y, bi0.y)), 0.f);
                float r2 = fmaxf(fmaf(e1.x, osv.x, fmaf(e1.y, osv.y, bi0.z)), 0.f);
                float r3 = fmaxf(fmaf(e1.z, osv.x, fmaf(e1.w, osv.y, bi0.w)), 0.f);
                float r4 = fmaxf(fmaf(e2.x, osv.x, fmaf(e2.y, osv.y, bi1.x)), 0.f);
                float r5 = fmaxf(fmaf(e2.z, osv.x, fmaf(e2.w, osv.y, bi1.y)), 0.f);
                float r6 = fmaxf(fmaf(e3.x, osv.x, fmaf(e3.y, osv.y, bi1.z)), 0.f);
                float r7 = fmaxf(fmaf(e3.z, osv.x, fmaf(e3.w, osv.y, bi1.w)), 0.f);
                float4 pk;
                pk.x = pkrtz(r0, r1);
                pk.y = pkrtz(r2, r3);
                pk.z = pkrtz(r4, r5);
                pk.w = pkrtz(r6, r7);
                int slot = (b ^ oct) & 15;
                *(float4*)&act_sh[(oct >> 2) * 512 + (oct & 3) * 128 + slot * 8] = pk;
            }
        }
        __syncthreads();

        // ---- segment 2: MFMA (part) + deriv (os update) ----
        {
            v4f c0 = {0.f, 0.f, 0.f, 0.f}, c1 = {0.f, 0.f, 0.f, 0.f};
            #pragma unroll
            for (int ks4 = 0; ks4 < 4; ++ks4) {
                v8h a  = *(const v8h*)&act_sh[a_off[ks4]];
                v8h w0 = *(const v8h*)&wp[ks4 * 32];
                v8h w1 = *(const v8h*)&wp[16 * KPAD + ks4 * 32];
                c0 = __builtin_amdgcn_mfma_f32_16x16x32_f16(a, w0, c0, 0, 0, 0);
                c1 = __builtin_amdgcn_mfma_f32_16x16x32_f16(a, w1, c1, 0, 0, 0);
            }
            *(v4f*)&part[(wv * 2 + 0) * 256 + lane * 4] = c0;
            *(v4f*)&part[(wv * 2 + 1) * 256 + lane * 4] = c1;
        }
        #pragma unroll
        for (int ii = 0; ii < 2; ++ii) {
            int task = t + ii * NTHR;
            if (task < NOSC * NB * 2) {         // 1600 tasks
                int o = task >> 5, r = task & 31, b = r >> 1, d = r & 1;
                const _Float16* dr = &dec_sh[(o * 2 + d) * 40];
                float acc0 = 0.f, acc1 = 0.f;
                #pragma unroll
                for (int c = 0; c < 5; ++c) {
                    int oct = o * 5 + c;
                    int base = (oct >> 2) * 512 + (oct & 3) * 128 + (((b ^ oct) & 15) * 8);
                    float4 af = *(const float4*)&act_sh[base];
                    float4 df = *(const float4*)&dr[c * 8];
                    acc0 = fdot2f(af.x, df.x, acc0);
                    acc1 = fdot2f(af.y, df.y, acc1);
                    acc0 = fdot2f(af.z, df.z, acc0);
                    acc1 = fdot2f(af.w, df.w, acc1);
                }
                os_sh[o * 32 + r] += 0.001f * (acc0 + acc1);
            }
        }
        __syncthreads();
    }
    // ---- epilogue: C for final step ----
    do_C(NSTEP - 1);
}

extern "C" void kernel_launch(void* const* d_in, const int* in_sizes, int n_in,
                              void* d_out, int out_size, void* d_ws, size_t ws_size,
                              hipStream_t stream) {
    (void)in_sizes; (void)n_in; (void)d_ws; (void)ws_size; (void)out_size;
    const float* x_     = (const float*)d_in[0];
    const float* fc1_w  = (const float*)d_in[1];
    const float* fc1_b  = (const float*)d_in[2];
    const float* fc2_w  = (const float*)d_in[3];
    const float* fc2_b  = (const float*)d_in[4];
    const float* fc3_w  = (const float*)d_in[5];
    const float* fc3_b  = (const float*)d_in[6];
    const float* fcd_w  = (const float*)d_in[7];
    const float* fcd_b  = (const float*)d_in[8];
    const float* enc    = (const float*)d_in[9];
    const float* oscb   = (const float*)d_in[10];
    const float* dec    = (const float*)d_in[11];
    const float* fc4_w  = (const float*)d_in[12];
    const float* fc4_b  = (const float*)d_in[13];
    const float* fc5_w  = (const float*)d_in[14];
    const float* fc5_b  = (const float*)d_in[15];
    float* out = (float*)d_out;

    hipLaunchKernelGGL(prep_f16, dim3(256), dim3(256), 0, stream, fc4_w);
    hipLaunchKernelGGL(net_main, dim3(BATCH / NB), dim3(NTHR), 0, stream,
                       x_, fc1_w, fc1_b, fc2_w, fc2_b, fc3_w, fc3_b,
                       fcd_w, fcd_b, enc, oscb, dec, fc4_b,
                       fc5_w, fc5_b, out);
}